// Round 6
// baseline (517.322 us; speedup 1.0000x reference)
//
#include <hip/hip_runtime.h>
#include <math.h>

// 2-layer ReLU RNN, B=256, T=1000 (input 800 + zero pad), H=128, F=5.
// R21: barrier-halving via SELF-CONTAINED engine waves. R20 (429us, 885cyc/
// step) spent ~550cyc/step on latency + an 8-wave barrier EVERY step; the
// only per-step dep was the intra-pair h-vector share. Now each engine is
// ONE wave (lane: c=lane&1 col-half of 64, rg=lane>>1, 4 rows rg*4+(j^2c),
// 128 fdot2, ONE DPP xor1 level -> lane owns contiguous rows rg*4+2c..+1;
// wp stays 64 VGPR), so the h0->h0 / h1->h1 recurrence syncs via the wave's
// own lgkmcnt. Cross-engine deps all have >=2-step slack (h0->A: 2..17;
// A->h1: 3; h1->y: >=6) => __syncthreads only EVERY 2 STEPS, 4-wave convoy
// (was 8). Audit under +-1-step skew: ring0 writes s..s+1 vs A reads
// s_A-17..s_A-2 (gap>=1, <32); ring1 writes vs y reads (gap 1..17); A_f
// writes s_A-17..s_A-2 vs h1 reads s_A-21..s_A-20 (gap>=3) - all disjoint
// mod 32. SK1=20 >= required 19. Bursts at 17+16k (A) / 37+16k (y), both
// odd = 2nd slot of a barrier window.
// Waves (256 thr, 1/SIMD): wv0=h0(+x-dot), wv1=h1, wv2=A-MFMA rows 0-63,
// wv3=A-MFMA rows 64-127 + y. A-engine = mfma_f32_16x16x32_f16 (R20-
// verified layouts). History: issue floor ~130cyc/SIMD/step; R20 convoy+
// latency was the wall, not issue.

#define TT    1000
#define TIN   800
#define HD    128
#define NF    5
#define BATCH 256
#define RS    136           // h16 ring row stride (272B)
#define AS    132           // f32 A-ring row stride (528B)
#define SK1   20            // h1 skew: h1[u] computed at step u+20
#define NSTEP (TT + SK1)    // 1020 steps (even)

typedef _Float16 h16x2 __attribute__((ext_vector_type(2)));
typedef _Float16 h16x8 __attribute__((ext_vector_type(8)));
typedef float    f32x4 __attribute__((ext_vector_type(4)));

template<int CTRL>
__device__ __forceinline__ float dpp_mov(float v) {
    union { float f; int i; } u, r;
    u.f = v;
    r.i = __builtin_amdgcn_update_dpp(0, u.i, CTRL, 0xF, 0xF, true);
    return r.f;
}

__global__ __launch_bounds__(256, 1) void rnn_sc(
    const float* __restrict__ x,        // [256,800,5]
    const float* __restrict__ h_state,  // [2,256,128]
    const float* __restrict__ w_ih0,    // [128,5]
    const float* __restrict__ w_hh0,    // [128,128]
    const float* __restrict__ b_ih0,    // [128]
    const float* __restrict__ b_hh0,    // [128]
    const float* __restrict__ w_ih1,    // [128,128]
    const float* __restrict__ w_hh1,    // [128,128]
    const float* __restrict__ b_ih1,    // [128]
    const float* __restrict__ b_hh1,    // [128]
    const float* __restrict__ w_out,    // [1,128]
    const float* __restrict__ b_out,    // [1]
    float* __restrict__ out)            // [204800 y] ++ [65536 final states]
{
    __shared__ __align__(16) _Float16 x_h[TIN * 8];      // 12.8 KB
    __shared__ __align__(16) _Float16 ring0[32][RS];     // h0 history
    __shared__ __align__(16) _Float16 ring1[32][RS];     // h1 history
    __shared__ __align__(16) float    A_f[32][AS];       // Wih1.h0 ring
    __shared__ float y_lds[TIN];

    const int tid  = threadIdx.x;
    const int bb   = blockIdx.x;
    const int wv   = tid >> 6;          // wave id 0..3 (one per SIMD)
    const int lane = tid & 63;

    // ---- stage x[bb] into LDS (fp16, stride 8, pads zero) ----
    for (int i = tid; i < TIN * 8; i += 256) x_h[i] = (_Float16)0.f;
    __syncthreads();
    for (int i = tid; i < TIN * NF; i += 256) {
        int t = i / 5, f = i - 5 * t;
        x_h[t * 8 + f] = (_Float16)x[bb * (TIN * NF) + i];
    }
    if (tid < HD) {
        ring0[31][tid] = (_Float16)h_state[bb * HD + tid];              // h0[-1]
        ring1[31][tid] = (_Float16)h_state[BATCH * HD + bb * HD + tid]; // h1[-1]
    }

    // ---- engine lane geometry (wv0,1): 2 col-halves x 32 row-groups ----
    const int c      = lane & 1;            // col half (64 cols)
    const int rg     = lane >> 1;           // row group (4 rows)
    const int g2     = 2 * c;               // XOR row map (flips on lane^1)
    const int base_r = rg * 4 + 2 * c;      // lane's final rows base_r, +1

    // ---- weight store: 64-VGPR block shared across wave roles ----
    union WU {
        h16x2 wp[4][32];    // wv0,1: rows rg*4+(j^g2), cols c*64..+63
        h16x8 af[4][4];     // wv2,3: Wih1 MFMA A-frags (64-row half)
    } W;
    h16x2 wo[16];           // wv3 only: wout (lives alongside af)
    h16x2 wxa[3], wxb[3];   // wv0: Wih0 rows base_r, base_r+1
    float bias0 = 0.f, bias1 = 0.f;

    if (wv < 2) {
        const float* Wsrc = (wv == 0) ? w_hh0 : w_hh1;
        #pragma unroll
        for (int j = 0; j < 4; ++j) {
            const float* rp = Wsrc + (rg * 4 + (j ^ g2)) * HD + c * 64;
            #pragma unroll
            for (int t = 0; t < 32; ++t) {
                h16x2 w2 = { (_Float16)rp[2 * t], (_Float16)rp[2 * t + 1] };
                W.wp[j][t] = w2;
            }
        }
        if (wv == 0) {
            #pragma unroll
            for (int k = 0; k < 3; ++k) {
                _Float16 a0 = (_Float16)w_ih0[base_r * NF + 2 * k];
                _Float16 a1 = (2 * k + 1 < NF) ? (_Float16)w_ih0[base_r * NF + 2 * k + 1] : (_Float16)0.f;
                _Float16 b0 = (_Float16)w_ih0[(base_r + 1) * NF + 2 * k];
                _Float16 b1 = (2 * k + 1 < NF) ? (_Float16)w_ih0[(base_r + 1) * NF + 2 * k + 1] : (_Float16)0.f;
                h16x2 wa = { a0, a1 }; wxa[k] = wa;
                h16x2 wb = { b0, b1 }; wxb[k] = wb;
            }
            bias0 = b_ih0[base_r] + b_hh0[base_r];
            bias1 = b_ih0[base_r + 1] + b_hh0[base_r + 1];
        } else {
            bias0 = b_ih1[base_r] + b_hh1[base_r];
            bias1 = b_ih1[base_r + 1] + b_hh1[base_r + 1];
        }
    } else {
        // A-frag (16x16x32): lane holds A[m = m0 + mt*16 + (lane&15)]
        //                                [k = kt*32 + (lane>>4)*8 + j]
        const int m0 = (wv == 2) ? 0 : 64;
        #pragma unroll
        for (int mt = 0; mt < 4; ++mt) {
            #pragma unroll
            for (int kt = 0; kt < 4; ++kt) {
                const float* rp = w_ih1 + (m0 + mt * 16 + (lane & 15)) * HD
                                + kt * 32 + (lane >> 4) * 8;
                h16x8 v;
                #pragma unroll
                for (int j = 0; j < 8; ++j) v[j] = (_Float16)rp[j];
                W.af[mt][kt] = v;
            }
        }
        if (wv == 3) {
            const int c4 = lane & 3;
            #pragma unroll
            for (int t = 0; t < 16; ++t) {
                h16x2 w2 = { (_Float16)w_out[c4 * 32 + 2 * t],
                             (_Float16)w_out[c4 * 32 + 2 * t + 1] };
                wo[t] = w2;
            }
        }
    }
    const float bout = b_out[0];

    float hfin0 = 0.f, hfin1 = 0.f;

    __syncthreads();

    // Self-contained matvec: 8 ds_read_b128 (2 addrs/wave, broadcast),
    // 4 rows x 32 fdot2, ONE DPP xor1 level -> full sums rows base_r, +1.
    auto matvec = [&](const _Float16* base, float& r0, float& r1) {
        h16x8 hv[8];
        #pragma unroll
        for (int u2 = 0; u2 < 8; ++u2)
            hv[u2] = *(const h16x8*)(base + c * 64 + 8 * u2);
        float a[4] = {0.f, 0.f, 0.f, 0.f};
        #pragma unroll
        for (int j = 0; j < 4; ++j) {
            float aj = 0.f;
            #pragma unroll
            for (int t = 0; t < 32; ++t) {
                h16x2 hp = { hv[t >> 2][2 * (t & 3)], hv[t >> 2][2 * (t & 3) + 1] };
                aj = __builtin_amdgcn_fdot2(W.wp[j][t], hp, aj, false);
            }
            a[j] = aj;
        }
        // xor1: partner (c^1) holds the other 64-col half of rows j^2
        a[0] += dpp_mov<0xB1>(a[2]);
        a[1] += dpp_mov<0xB1>(a[3]);
        r0 = a[0];      // row base_r
        r1 = a[1];      // row base_r + 1
    };

    auto body = [&](int s) {
        if (wv == 0) {
            // h0[s] = relu(Whh0.h0[s-1] + Wih0.x[s] + b)  (wave-internal dep)
            if (s < TT) {
                float v0, v1;
                matvec(&ring0[(s + 31) & 31][0], v0, v1);
                v0 += bias0; v1 += bias1;
                if (s < TIN) {
                    h16x8 xv = *(const h16x8*)(&x_h[s * 8]);
                    h16x2 xp0 = { xv[0], xv[1] };
                    h16x2 xp1 = { xv[2], xv[3] };
                    h16x2 xp2 = { xv[4], xv[5] };   // slot 5 is zero pad
                    float xc0 = __builtin_amdgcn_fdot2(wxa[2], xp2, 0.f, false);
                    xc0 = __builtin_amdgcn_fdot2(wxa[1], xp1, xc0, false);
                    xc0 = __builtin_amdgcn_fdot2(wxa[0], xp0, xc0, false);
                    float xc1 = __builtin_amdgcn_fdot2(wxb[2], xp2, 0.f, false);
                    xc1 = __builtin_amdgcn_fdot2(wxb[1], xp1, xc1, false);
                    xc1 = __builtin_amdgcn_fdot2(wxb[0], xp0, xc1, false);
                    v0 += xc0; v1 += xc1;
                }
                v0 = fmaxf(v0, 0.f);
                v1 = fmaxf(v1, 0.f);
                h16x2 hv = { (_Float16)v0, (_Float16)v1 };
                *(h16x2*)(&ring0[s & 31][base_r]) = hv;
                if (s == TT - 1) { hfin0 = v0; hfin1 = v1; }
            }
        } else if (wv == 1) {
            // h1[u] = relu(Whh1.h1[u-1] + A[u] + b), u = s - 20
            if (s >= SK1) {
                const int u = s - SK1;
                float v0, v1;
                matvec(&ring1[(u + 31) & 31][0], v0, v1);
                float2 av = *(const float2*)(&A_f[u & 31][base_r]);
                v0 = fmaxf(v0 + bias0 + av.x, 0.f);
                v1 = fmaxf(v1 + bias1 + av.y, 0.f);
                h16x2 hv = { (_Float16)v0, (_Float16)v1 };
                *(h16x2*)(&ring1[u & 31][base_r]) = hv;
                if (u == TT - 1) { hfin0 = v0; hfin1 = v1; }
            }
        } else {
            // A burst: A[ub..ub+15] = Wih1 . h0[ub..ub+15], ub = s-17 (odd s)
            if (s >= 17 && s <= 1009 && ((s - 17) & 15) == 0) {
                const int m0 = (wv == 2) ? 0 : 64;
                const int ub = s - 17;
                const int un = ub + (lane & 15);    // this lane's column step
                h16x8 bf[4];
                #pragma unroll
                for (int kt = 0; kt < 4; ++kt)
                    bf[kt] = *(const h16x8*)(&ring0[un & 31]
                                             [kt * 32 + (lane >> 4) * 8]);
                #pragma unroll
                for (int mt = 0; mt < 4; ++mt) {
                    f32x4 acc = {0.f, 0.f, 0.f, 0.f};
                    #pragma unroll
                    for (int kt = 0; kt < 4; ++kt)
                        acc = __builtin_amdgcn_mfma_f32_16x16x32_f16(
                            W.af[mt][kt], bf[kt], acc, 0, 0, 0);
                    if (un < TT)
                        *(f32x4*)(&A_f[un & 31]
                                  [m0 + mt * 16 + (lane >> 4) * 4]) = acc;
                }
            }
            // y burst (wv3): t = (s-37)+slot; h1[t] written at t+20 <= s-2
            if (wv == 3 && s >= 37 && s <= 821 && ((s - 37) & 15) == 0) {
                const int slot = lane >> 2;
                const int c4   = lane & 3;
                const int t    = (s - 37) + slot;
                const _Float16* rb = &ring1[t & 31][0] + c4 * 32;
                float z = 0.f;
                #pragma unroll
                for (int u2 = 0; u2 < 4; ++u2) {
                    h16x8 hv = *(const h16x8*)(rb + 8 * u2);
                    h16x2 hp0 = { hv[0], hv[1] };
                    h16x2 hp1 = { hv[2], hv[3] };
                    h16x2 hp2 = { hv[4], hv[5] };
                    h16x2 hp3 = { hv[6], hv[7] };
                    z = __builtin_amdgcn_fdot2(wo[4 * u2 + 0], hp0, z, false);
                    z = __builtin_amdgcn_fdot2(wo[4 * u2 + 1], hp1, z, false);
                    z = __builtin_amdgcn_fdot2(wo[4 * u2 + 2], hp2, z, false);
                    z = __builtin_amdgcn_fdot2(wo[4 * u2 + 3], hp3, z, false);
                }
                z += dpp_mov<0xB1>(z);    // xor1 (within quad)
                z += dpp_mov<0x4E>(z);    // xor2
                if (c4 == 0) y_lds[t] = 1.f / (1.f + expf(-(z + bout)));
            }
        }
    };

    // barrier every 2 steps: cross-engine deps have >=2-step slack (audited)
    for (int s2 = 0; s2 < NSTEP; s2 += 2) {
        body(s2);
        body(s2 + 1);
        __syncthreads();
    }

    // ---- epilogue: single global dump ----
    for (int i = tid; i < TIN; i += 256)
        out[bb * TIN + i] = y_lds[i];
    if (wv == 0)
        *(float2*)(&out[TIN * BATCH + bb * HD + base_r]) = make_float2(hfin0, hfin1);
    else if (wv == 1)
        *(float2*)(&out[TIN * BATCH + BATCH * HD + bb * HD + base_r]) = make_float2(hfin0, hfin1);
}

extern "C" void kernel_launch(void* const* d_in, const int* in_sizes, int n_in,
                              void* d_out, int out_size, void* d_ws, size_t ws_size,
                              hipStream_t stream) {
    (void)in_sizes; (void)n_in; (void)d_ws; (void)ws_size; (void)out_size;
    rnn_sc<<<dim3(BATCH), dim3(256), 0, stream>>>(
        (const float*)d_in[0],  (const float*)d_in[1],
        (const float*)d_in[2],  (const float*)d_in[3],
        (const float*)d_in[4],  (const float*)d_in[5],
        (const float*)d_in[6],  (const float*)d_in[7],
        (const float*)d_in[8],  (const float*)d_in[9],
        (const float*)d_in[10], (const float*)d_in[11],
        (float*)d_out);
}